// Round 1
// baseline (1667.755 us; speedup 1.0000x reference)
//
#include <hip/hip_runtime.h>

// Problem constants (from reference setup_inputs): B=8, C=16, H=W=256
#define BB 8
#define CC 16
#define HH 256
#define WW 256
#define HW (HH * WW)

// One thread per (b, i, j). Compute bilinear scatter weights once, loop over
// the 16 channels doing 4 atomicAdds each. Output crop [1:h+1,1:w+1] is
// folded into the index math: out_row = i0+di-1, bounds-checked.
__global__ __launch_bounds__(256) void invgrid_scatter(
    const float* __restrict__ x,
    const float* __restrict__ inv_grid,
    float* __restrict__ out)
{
    const int idx = blockIdx.x * 256 + threadIdx.x;   // b*H*W + i*W + j
    const int j = idx & (WW - 1);
    const int i = (idx >> 8) & (HH - 1);
    const int b = idx >> 16;

    // inv_grid is (B,H,W,2) contiguous -> float2 per (b,i,j)
    const float2 g2 = ((const float2*)inv_grid)[idx];
    const float g0 = (g2.x + 1.0f) * 0.5f;
    const float g1 = (g2.y + 1.0f) * 0.5f;

    // ci = clip(g0*h + 1, 0, h+1-2eps); h+1-2e-10 rounds to 257.0f in fp32
    float ci = fminf(fmaxf(fmaf(g0, (float)HH, 1.0f), 0.0f), 257.0f);
    float cj = fminf(fmaxf(fmaf(g1, (float)WW, 1.0f), 0.0f), 257.0f);

    const int i0 = (int)floorf(ci);
    const int j0 = (int)floorf(cj);

    // weights exactly as reference: relu(1 - |c - (i0+d)|)
    const float wi0 = fmaxf(0.0f, 1.0f - fabsf(ci - (float)i0));
    const float wi1 = fmaxf(0.0f, 1.0f - fabsf(ci - (float)(i0 + 1)));
    const float wj0 = fmaxf(0.0f, 1.0f - fabsf(cj - (float)j0));
    const float wj1 = fmaxf(0.0f, 1.0f - fabsf(cj - (float)(j0 + 1)));

    const float w00 = wi0 * wj0, w01 = wi0 * wj1;
    const float w10 = wi1 * wj0, w11 = wi1 * wj1;

    // cropped output coordinates
    const int r0 = i0 - 1, r1 = i0;      // rows for di = 0, 1
    const int c0 = j0 - 1, c1 = j0;      // cols for dj = 0, 1
    const bool vr0 = (unsigned)r0 < HH, vr1 = (unsigned)r1 < HH;
    const bool vc0 = (unsigned)c0 < WW, vc1 = (unsigned)c1 < WW;
    const bool v00 = vr0 & vc0, v01 = vr0 & vc1;
    const bool v10 = vr1 & vc0, v11 = vr1 & vc1;

    const int o00 = r0 * WW + c0, o01 = r0 * WW + c1;
    const int o10 = r1 * WW + c0, o11 = r1 * WW + c1;

    const float* xp = x + (size_t)b * CC * HW + i * WW + j;
    float* op = out + (size_t)b * CC * HW;

#pragma unroll
    for (int c = 0; c < CC; ++c) {
        const float xv = xp[(size_t)c * HW];
        float* ob = op + (size_t)c * HW;
        if (v00) atomicAdd(ob + o00, xv * w00);
        if (v01) atomicAdd(ob + o01, xv * w01);
        if (v10) atomicAdd(ob + o10, xv * w10);
        if (v11) atomicAdd(ob + o11, xv * w11);
    }
}

extern "C" void kernel_launch(void* const* d_in, const int* in_sizes, int n_in,
                              void* d_out, int out_size, void* d_ws, size_t ws_size,
                              hipStream_t stream) {
    const float* x        = (const float*)d_in[0];
    const float* inv_grid = (const float*)d_in[1];
    float* out            = (float*)d_out;

    // d_out is poisoned with 0xAA before every timed launch — zero it.
    hipMemsetAsync(d_out, 0, (size_t)out_size * sizeof(float), stream);

    const int n_threads = BB * HH * WW;          // 524288
    invgrid_scatter<<<n_threads / 256, 256, 0, stream>>>(x, inv_grid, out);
}